// Round 1
// baseline (695.930 us; speedup 1.0000x reference)
//
#include <hip/hip_runtime.h>
#include <stdint.h>

#define COLS 16384
#define POOLCAP 248          // trimmed from 256 so ring+pool fit 4 blocks/CU (E[pool]~74)
#define RING 8               // ring slots per wave, 1 KB each -> ~8 KB in flight per wave
#define NCHUNK 48            // 48 chunks x 256 floats cover cols [4096, 16384)
typedef unsigned long long u64;
typedef float vf4 __attribute__((ext_vector_type(4)));

// Order-preserving float32 -> uint32 mapping (ascending float == ascending uint).
__device__ __forceinline__ uint32_t f2key(float x) {
  uint32_t u = __float_as_uint(x);
  u ^= (uint32_t)((int32_t)u >> 31) | 0x80000000u;
  return u;
}

__global__ __launch_bounds__(256, 4) void KNNC_20272245637217_kernel(
    const float* __restrict__ dist,
    const int* __restrict__ labels,
    int* __restrict__ out) {
  const int wave = threadIdx.x >> 6;   // 4 waves/block, one row each
  const int lane = threadIdx.x & 63;
  const int row  = blockIdx.x * 4 + wave;

  // LDS: 4*8*1KB ring (32KB) + 4*248*8B pool (7.75KB) + cnt = 40.7KB -> 4 blocks/CU
  __shared__ vf4 ringv[4][RING][64];
  __shared__ u64 poolK[4][POOLCAP];    // (sortable value bits << 32) | column idx
  __shared__ int cnt[4];
  if (threadIdx.x < 4) cnt[threadIdx.x] = 0;
  __syncthreads();                     // barrier BEFORE any loads are issued

  const float* __restrict__ rowp = dist + (size_t)row * COLS;
  const vf4* __restrict__ rp = (const vf4*)rowp;

  // ---- Prefix (cols 0..4095) stays in registers: needed twice (T, then pushes) ----
  vf4 A8[8], B8[8];
#define LOAD8(b, buf) { _Pragma("unroll") \
  for (int u = 0; u < 8; ++u) (buf)[u] = __builtin_nontemporal_load(rp + (b)*512 + u*64 + lane); }

  LOAD8(0, A8)
  LOAD8(1, B8)

  // ---- Deep-MLP streaming of cols 4096..16383: async DMA into the LDS ring. ----
  // global_load_lds is VGPR-free and lets us keep ~8 outstanding KB per wave
  // (vs 128-256 B with the old register double-buffer -> the 8x BW shortfall).
  // LDS dest is wave-uniform base + lane*16B (linear) -- the required layout.
#define ISSUE(c) __builtin_amdgcn_global_load_lds( \
    (const __attribute__((address_space(1))) void*)(rowp + 4096 + (c) * 256 + lane * 4), \
    (__attribute__((address_space(3))) void*)(&ringv[wave][(c) & (RING - 1)][0]), \
    16, 0, 0);

  #pragma unroll
  for (int c = 0; c < RING; ++c) { ISSUE(c) }
  __builtin_amdgcn_sched_barrier(0);   // pin the prefill issues before Stage A compute

  // ---- Stage A: lane-min over first 4096 elements (ring fill hides under this) ----
  float m = __builtin_inff();
  #pragma unroll
  for (int u = 0; u < 8; ++u)
    m = fminf(m, fminf(fminf(A8[u].x, A8[u].y), fminf(A8[u].z, A8[u].w)));
  #pragma unroll
  for (int u = 0; u < 8; ++u)
    m = fminf(m, fminf(fminf(B8[u].x, B8[u].y), fminf(B8[u].z, B8[u].w)));

  // ---- T = exact 16th smallest of the 64 lane minima (bitonic sort, 21 stages) ----
  // T >= row's true 16th smallest: the 16 smallest lane-minima are 16 distinct
  // row elements <= T. Expected pool size ~74, P(>248) negligible.
  float v = m;
  #pragma unroll
  for (int k = 2; k <= 64; k <<= 1) {
    #pragma unroll
    for (int j = k >> 1; j >= 1; j >>= 1) {
      float o = __shfl_xor(v, j);
      bool keepMin = (((lane & j) == 0) == ((lane & k) == 0));
      v = keepMin ? fminf(v, o) : fmaxf(v, o);
    }
  }
  const float T = __shfl(v, 15);

#define PUSH(x, c) { if ((x) <= T) { \
    int _s = atomicAdd(&cnt[wave], 1); \
    if (_s < POOLCAP) poolK[wave][_s] = (((u64)f2key(x)) << 32) | (u64)(uint32_t)(c); } }
#define PROC8(buf, b) { _Pragma("unroll") \
  for (int u = 0; u < 8; ++u) { \
    vf4 w = (buf)[u]; \
    float mn = fminf(fminf(w.x, w.y), fminf(w.z, w.w)); \
    if (mn <= T) { \
      int col = ((b)*8 + u) * 256 + lane * 4; \
      PUSH(w.x, col) PUSH(w.y, col+1) PUSH(w.z, col+2) PUSH(w.w, col+3) \
    } } }

  // ---- Re-scan register-resident prefix for pushes (cols 0..4095) ----
  PROC8(A8, 0)
  PROC8(B8, 1)

  // ---- Ring loop: counted vmcnt waits, never drained to 0 in steady state. ----
  // Iter i: wait until chunk i has landed (7 newer DMAs stay in flight), read
  // the 16B/lane slot, filter, then refill the slot with chunk i+8.
  // lgkmcnt(0) before the refill: the DMA's LDS-write (vmem pipe) is not
  // ordered against ds_read, so the read must be architecturally complete.
#define RPROC(i, W) { \
    asm volatile("s_waitcnt vmcnt(" #W ")" ::: "memory"); \
    vf4 w = ringv[wave][(i) & (RING - 1)][lane]; \
    float mn = fminf(fminf(w.x, w.y), fminf(w.z, w.w)); \
    if (mn <= T) { \
      int col = 4096 + (i) * 256 + lane * 4; \
      PUSH(w.x, col) PUSH(w.y, col+1) PUSH(w.z, col+2) PUSH(w.w, col+3) \
    } }

  #pragma unroll 8
  for (int i = 0; i < NCHUNK - RING; ++i) {
    RPROC(i, 7)
    asm volatile("s_waitcnt lgkmcnt(0)" ::: "memory");
    ISSUE(i + RING)
  }
  // Tail: 8 remaining chunks, waits step down 7 -> 0 so each chunk is awaited.
  RPROC(40, 7) RPROC(41, 6) RPROC(42, 5) RPROC(43, 4)
  RPROC(44, 3) RPROC(45, 2) RPROC(46, 1) RPROC(47, 0)

  __syncthreads();

  // ---- Exact top-16 extraction (u64 keys reproduce top_k's index tie-break) ----
  int C = cnt[wave];
  if (C > POOLCAP) C = POOLCAP;   // defensive; C >= 16 guaranteed by T's construction

  u64 key[4];
  #pragma unroll
  for (int t = 0; t < 4; ++t) {
    int p = lane + 64 * t;
    key[t] = (p < C) ? poolK[wave][p] : ~0ULL;
  }

  u64 myWin = ~0ULL;
  for (int r = 0; r < 16; ++r) {
    u64 k = key[0];
    k = (key[1] < k) ? key[1] : k;
    k = (key[2] < k) ? key[2] : k;
    k = (key[3] < k) ? key[3] : k;
    #pragma unroll
    for (int off = 32; off >= 1; off >>= 1) {
      u64 o = __shfl_xor(k, off);
      k = (o < k) ? o : k;
    }
    if (lane == r) myWin = k;           // lane r records the r-th smallest
    #pragma unroll
    for (int t = 0; t < 4; ++t)
      if (key[t] == k) key[t] = ~0ULL;  // keys unique (idx in low bits)
  }

  // ---- Majority vote over the 16 winners' labels ----
  int myLabel = 0;
  if (lane < 16) myLabel = labels[(uint32_t)myWin];  // low 32 bits = column idx

  int c = 0;
  #pragma unroll
  for (int s = 0; s < 16; ++s) {
    int ls = __shfl(myLabel, s);
    c += (ls == myLabel) ? 1 : 0;
  }
  // maximize count, then minimize label (argmax-first semantics)
  int vkey = (lane < 16) ? ((c << 7) | (127 - myLabel)) : 0;
  #pragma unroll
  for (int off = 32; off >= 1; off >>= 1) {
    int o = __shfl_xor(vkey, off);
    vkey = (o > vkey) ? o : vkey;
  }
  if (lane == 0) out[row] = 127 - (vkey & 127);
}

extern "C" void kernel_launch(void* const* d_in, const int* in_sizes, int n_in,
                              void* d_out, int out_size, void* d_ws, size_t ws_size,
                              hipStream_t stream) {
  const float* dist   = (const float*)d_in[0];
  const int*   labels = (const int*)d_in[1];
  int*         out    = (int*)d_out;
  const int rows = out_size;          // 8192
  KNNC_20272245637217_kernel<<<rows / 4, 256, 0, stream>>>(dist, labels, out);
}

// Round 2
// 676.052 us; speedup vs baseline: 1.0294x; 1.0294x over previous
//
#include <hip/hip_runtime.h>
#include <stdint.h>

#define COLS 16384
#define POOLCAP 256
typedef unsigned long long u64;
typedef float vf4 __attribute__((ext_vector_type(4)));

// Order-preserving float32 -> uint32 mapping (ascending float == ascending uint).
__device__ __forceinline__ uint32_t f2key(float x) {
  uint32_t u = __float_as_uint(x);
  u ^= (uint32_t)((int32_t)u >> 31) | 0x80000000u;
  return u;
}

// 6-bit bit-reversal: per-row start-chunk phase. Rows within a block land
// 16-32 KB apart; consecutive blocks spread the mid address bits maximally.
__device__ __forceinline__ int bitrev6(int r) {
  return ((r & 1) << 5) | ((r & 2) << 3) | ((r & 4) << 1) |
         ((r & 8) >> 1) | ((r & 16) >> 3) | ((r & 32) >> 5);
}

__global__ __launch_bounds__(256, 4) void KNNC_20272245637217_kernel(
    const float* __restrict__ dist,
    const int* __restrict__ labels,
    int* __restrict__ out) {
  const int wave = threadIdx.x >> 6;   // 4 waves/block, one row each
  const int lane = threadIdx.x & 63;
  const int row  = blockIdx.x * 4 + wave;

  // Phase-decorrelation: all 4096 resident waves otherwise stream at stride
  // exactly 64 KB starting from the SAME column simultaneously -> the HBM
  // channel/bank hash sees identical low/mid address bits chip-wide and
  // serializes (measured: ~1.6 TB/s, 4x off roofline, prefetch-insensitive).
  // Rotating each row's chunk order by a bit-reversed phase spreads the
  // instantaneous footprint across all channels. Order is correctness-free:
  // T only needs SOME 4096 distinct columns; the pool sorts by (value,col).
  const int phase = bitrev6(row & 63);

  __shared__ u64 poolK[4][POOLCAP];    // (sortable value bits << 32) | column idx
  __shared__ int cnt[4];
  if (threadIdx.x < 4) cnt[threadIdx.x] = 0;
  __syncthreads();

  const vf4* __restrict__ rp = (const vf4*)(dist + (size_t)row * COLS);

  // Logical chunk k (0..63) -> physical 1-KB chunk of the row.
#define KP(b, u) ((((b) * 8 + (u)) + phase) & 63)

  // Two 8-wide register buffers; every dist byte is loaded exactly once.
  // Plain cached loads (NT dropped): stay in the measured-good load regime.
  vf4 A8[8], B8[8];
#define LOAD8(b, buf) { _Pragma("unroll") \
  for (int u = 0; u < 8; ++u) (buf)[u] = rp[KP(b, u) * 64 + lane]; }

  LOAD8(0, A8)
  LOAD8(1, B8)

  // ---- Stage A: lane-min over 4096 distinct elements (chunks phase..phase+15) ----
  float m = __builtin_inff();
  #pragma unroll
  for (int u = 0; u < 8; ++u)
    m = fminf(m, fminf(fminf(A8[u].x, A8[u].y), fminf(A8[u].z, A8[u].w)));
  #pragma unroll
  for (int u = 0; u < 8; ++u)
    m = fminf(m, fminf(fminf(B8[u].x, B8[u].y), fminf(B8[u].z, B8[u].w)));

  // ---- T = exact 16th smallest of the 64 lane minima (bitonic sort, 21 stages) ----
  // T >= row's true 16th smallest: the 16 smallest lane-minima are 16 distinct
  // row elements <= T. Expected pool size ~74, P(>256) ~ 1e-11 per row.
  float v = m;
  #pragma unroll
  for (int k = 2; k <= 64; k <<= 1) {
    #pragma unroll
    for (int j = k >> 1; j >= 1; j >>= 1) {
      float o = __shfl_xor(v, j);
      bool keepMin = (((lane & j) == 0) == ((lane & k) == 0));
      v = keepMin ? fminf(v, o) : fmaxf(v, o);
    }
  }
  const float T = __shfl(v, 15);

#define PUSH(x, c) { if ((x) <= T) { \
    int _s = atomicAdd(&cnt[wave], 1); \
    if (_s < POOLCAP) poolK[wave][_s] = (((u64)f2key(x)) << 32) | (u64)(uint32_t)(c); } }
#define PROC8(buf, b) { _Pragma("unroll") \
  for (int u = 0; u < 8; ++u) { \
    vf4 w = (buf)[u]; \
    float mn = fminf(fminf(w.x, w.y), fminf(w.z, w.w)); \
    if (mn <= T) { \
      int col = KP(b, u) * 256 + lane * 4; \
      PUSH(w.x, col) PUSH(w.y, col+1) PUSH(w.z, col+2) PUSH(w.w, col+3) \
    } } }

  // ---- Stage B: double-buffered process/prefetch; batches 0,1 already resident ----
  PROC8(A8, 0)
  LOAD8(2, A8)
  PROC8(B8, 1)
  LOAD8(3, B8)
  PROC8(A8, 2)
  LOAD8(4, A8)
  PROC8(B8, 3)
  LOAD8(5, B8)
  PROC8(A8, 4)
  LOAD8(6, A8)
  PROC8(B8, 5)
  LOAD8(7, B8)
  PROC8(A8, 6)
  PROC8(B8, 7)

  __syncthreads();

  // ---- Exact top-16 extraction (u64 keys reproduce top_k's index tie-break) ----
  int C = cnt[wave];
  if (C > POOLCAP) C = POOLCAP;   // defensive; C >= 16 guaranteed by T's construction

  u64 key[4];
  #pragma unroll
  for (int t = 0; t < 4; ++t) {
    int p = lane + 64 * t;
    key[t] = (p < C) ? poolK[wave][p] : ~0ULL;
  }

  u64 myWin = ~0ULL;
  for (int r = 0; r < 16; ++r) {
    u64 k = key[0];
    k = (key[1] < k) ? key[1] : k;
    k = (key[2] < k) ? key[2] : k;
    k = (key[3] < k) ? key[3] : k;
    #pragma unroll
    for (int off = 32; off >= 1; off >>= 1) {
      u64 o = __shfl_xor(k, off);
      k = (o < k) ? o : k;
    }
    if (lane == r) myWin = k;           // lane r records the r-th smallest
    #pragma unroll
    for (int t = 0; t < 4; ++t)
      if (key[t] == k) key[t] = ~0ULL;  // keys unique (idx in low bits)
  }

  // ---- Majority vote over the 16 winners' labels ----
  int myLabel = 0;
  if (lane < 16) myLabel = labels[(uint32_t)myWin];  // low 32 bits = column idx

  int c = 0;
  #pragma unroll
  for (int s = 0; s < 16; ++s) {
    int ls = __shfl(myLabel, s);
    c += (ls == myLabel) ? 1 : 0;
  }
  // maximize count, then minimize label (argmax-first semantics)
  int vkey = (lane < 16) ? ((c << 7) | (127 - myLabel)) : 0;
  #pragma unroll
  for (int off = 32; off >= 1; off >>= 1) {
    int o = __shfl_xor(vkey, off);
    vkey = (o > vkey) ? o : vkey;
  }
  if (lane == 0) out[row] = 127 - (vkey & 127);
}

extern "C" void kernel_launch(void* const* d_in, const int* in_sizes, int n_in,
                              void* d_out, int out_size, void* d_ws, size_t ws_size,
                              hipStream_t stream) {
  const float* dist   = (const float*)d_in[0];
  const int*   labels = (const int*)d_in[1];
  int*         out    = (int*)d_out;
  const int rows = out_size;          // 8192
  KNNC_20272245637217_kernel<<<rows / 4, 256, 0, stream>>>(dist, labels, out);
}